// Round 8
// baseline (413.444 us; speedup 1.0000x reference)
//
#include <hip/hip_runtime.h>

// Neural-CA update step, MI355X/gfx950.
// ca_prep: pack W1(+b1)/W2 into MFMA bf16 fragments in d_ws.
// ca_update: 16x16 tile, fp32 perceive -> bf16 MFMA MLP -> out, ws_alpha, ws_pre.
//   v8 (resubmit; round-7 run died to container infra, no data): NO x-tile in
//   LDS. x is L3-resident (64MB < 256MB, re-read each iter), so perceive loads
//   its 9 neighbors per channel-quad straight from global.
//     * LDS = weights 20,480B + yfs 8,448B ~= 29KB; ONE barrier total
//     * pre-mask alpha folds into the cq=0 neighbor loads (.w lane)
//     * epilogue xc / rand_u read direct from global (coalesced, L3-hit)
//     * register demand drops (no staging temps / xcr / lsr) -> fits
//       (256,3)'s 170-reg budget with headroom -> kills the residual spill
//       (v7: WRITE 170MB vs ~70 real; excess = scratch writebacks)
//     * shuffle h-transpose + MFMA s-loop unchanged from v6/v7
// ca_fix: one wave per worklist entry recomputes exact fp32 alpha.
// ca_mask: branchless 3x3 max; only ZEROES dead pixels.

#define NC 16
#define NHID 128
#define NPIX (16 * 256 * 256)
#define MG 0.04f
#define MAXFIX 65536

typedef __attribute__((ext_vector_type(8))) short s8b;   // 8 x bf16 (4 VGPRs)
typedef __attribute__((ext_vector_type(4))) float f4;

__device__ __forceinline__ unsigned short f2bf(float f) {
    union { float f; unsigned int u; } v; v.f = f;
    unsigned int r = (v.u + 0x7FFFu + ((v.u >> 16) & 1u)) >> 16;  // RNE
    return (unsigned short)r;
}
__device__ __forceinline__ unsigned int pack2(float a, float b) {
    return (unsigned int)f2bf(a) | ((unsigned int)f2bf(b) << 16);
}

// ---------------- prep: pack weights into MFMA fragment order ----------------
__global__ __launch_bounds__(256) void ca_prep(
    const float* __restrict__ W1, const float* __restrict__ b1,
    const float* __restrict__ W2, uint4* __restrict__ w1p, uint4* __restrict__ w2p)
{
    const int tid = threadIdx.x;
    if (blockIdx.x == 0) {
        for (int idx = tid; idx < 1024; idx += 256) {
            const int fid = idx >> 6, lane = idx & 63;
            const int k0 = fid >> 3, mt = fid & 7;
            const int q = lane >> 4, i = lane & 15;
            unsigned int u[4];
            #pragma unroll
            for (int jp = 0; jp < 4; ++jp) {
                int k = k0 * 32 + q * 8 + jp * 2;
                float v0 = (k < 48) ? W1[k * 128 + mt * 16 + i] : ((k == 48) ? b1[mt * 16 + i] : 0.f);
                k++;
                float v1 = (k < 48) ? W1[k * 128 + mt * 16 + i] : ((k == 48) ? b1[mt * 16 + i] : 0.f);
                u[jp] = pack2(v0, v1);
            }
            w1p[idx] = make_uint4(u[0], u[1], u[2], u[3]);
        }
    } else {
        for (int idx = tid; idx < 256; idx += 256) {
            const int k2 = idx >> 6, lane = idx & 63;
            const int q = lane >> 4, i = lane & 15;
            unsigned int u[4];
            #pragma unroll
            for (int jp = 0; jp < 4; ++jp) {
                const int k = k2 * 32 + q * 8 + jp * 2;
                u[jp] = pack2(W2[k * 16 + i], W2[(k + 1) * 16 + i]);
            }
            w2p[idx] = make_uint4(u[0], u[1], u[2], u[3]);
        }
    }
}

// ---------------- main update kernel ----------------
__global__ __launch_bounds__(256, 3) void ca_update(
    const float* __restrict__ x, const float* __restrict__ b2,
    const float* __restrict__ rand_u, const uint4* __restrict__ w1p,
    const uint4* __restrict__ w2p, float* __restrict__ out,
    float* __restrict__ ws_alpha, unsigned char* __restrict__ ws_pre,
    unsigned int* __restrict__ fix_cnt, unsigned int* __restrict__ fix_list)
{
    __shared__ __align__(16) uint4 wsm[1280];                  // 20,480 B weights
    __shared__ __align__(16) unsigned short yfs[4 * 2 * 528];  // 8,448 B y B-frags

    const int tid  = threadIdx.x;
    const int lane = tid & 63;
    const int li   = lane & 15;
    const int lq   = lane >> 4;
    const int wv   = tid >> 6;
    const int tx   = tid & 15, ty = tid >> 4;
    const int w0 = blockIdx.x * 16, h0 = blockIdx.y * 16, bb = blockIdx.z;

    // ---- stage weight fragments into LDS (w2p contiguous after w1p) ----
    for (int i = tid; i < 1280; i += 256)
        wsm[i] = w1p[i];

    float b2v[4];
    #pragma unroll
    for (int r = 0; r < 4; ++r) b2v[r] = b2[lq * 4 + r];

    // ---- perceive straight from global (x is L3-resident) ----
    const int gh = h0 + ty, gw = w0 + tx;
    const size_t gpix = ((size_t)bb * 256 + gh) * 256 + gw;
    const float* xb = x + (size_t)bb * 256 * 256 * NC;

    // neighbor validity + base offsets (element offset of quad 0)
    bool nv[3][3];
    size_t nb[3][3];
    #pragma unroll
    for (int dy = 0; dy < 3; ++dy) {
        const int hh = gh + dy - 1;
        const bool hv = (hh >= 0) && (hh < 256);
        #pragma unroll
        for (int dxx = 0; dxx < 3; ++dxx) {
            const int ww = gw + dxx - 1;
            nv[dy][dxx] = hv && (ww >= 0) && (ww < 256);
            nb[dy][dxx] = ((size_t)(hv ? hh : 0) * 256 + (size_t)((ww >= 0 && ww < 256) ? ww : 0)) * NC;
        }
    }

    unsigned int yu[24];
    float am = 0.f;
    #pragma unroll
    for (int cq = 0; cq < 4; ++cq) {
        const int co = cq * 4;
        const float4 z4 = make_float4(0.f, 0.f, 0.f, 0.f);
        float4 vmm = nv[0][0] ? *(const float4*)(xb + nb[0][0] + co) : z4;
        float4 vm0 = nv[0][1] ? *(const float4*)(xb + nb[0][1] + co) : z4;
        float4 vmp = nv[0][2] ? *(const float4*)(xb + nb[0][2] + co) : z4;
        float4 v0m = nv[1][0] ? *(const float4*)(xb + nb[1][0] + co) : z4;
        float4 vcc = nv[1][1] ? *(const float4*)(xb + nb[1][1] + co) : z4;
        float4 v0p = nv[1][2] ? *(const float4*)(xb + nb[1][2] + co) : z4;
        float4 vpm = nv[2][0] ? *(const float4*)(xb + nb[2][0] + co) : z4;
        float4 vp0 = nv[2][1] ? *(const float4*)(xb + nb[2][1] + co) : z4;
        float4 vpp = nv[2][2] ? *(const float4*)(xb + nb[2][2] + co) : z4;
        if (cq == 0) {
            // pre-life mask: 3x3 max of alpha (channel 3 = .w of quad 0), exact fp32
            am = vmm.w;
            am = fmaxf(am, vm0.w); am = fmaxf(am, vmp.w);
            am = fmaxf(am, v0m.w); am = fmaxf(am, vcc.w); am = fmaxf(am, v0p.w);
            am = fmaxf(am, vpm.w); am = fmaxf(am, vp0.w); am = fmaxf(am, vpp.w);
        }
        const float* pmm = (const float*)&vmm; const float* pm0 = (const float*)&vm0;
        const float* pmp = (const float*)&vmp; const float* p0m = (const float*)&v0m;
        const float* pcc = (const float*)&vcc; const float* p0p = (const float*)&v0p;
        const float* ppm = (const float*)&vpm; const float* pp0 = (const float*)&vp0;
        const float* ppp = (const float*)&vpp;
        float yl[12];
        #pragma unroll
        for (int cc = 0; cc < 4; ++cc) {
            const float xmm = pmm[cc], xm0 = pm0[cc], xmp = pmp[cc];
            const float x0m = p0m[cc], xcc = pcc[cc], x0p = p0p[cc];
            const float xpm = ppm[cc], xp0 = pp0[cc], xpp = ppp[cc];
            yl[cc * 3 + 0] = xcc;
            yl[cc * 3 + 1] = ((xmp - xmm) + 2.f * (x0p - x0m) + (xpp - xpm)) * 0.125f;
            yl[cc * 3 + 2] = ((xpm - xmm) + 2.f * (xp0 - xm0) + (xpp - xmp)) * 0.125f;
        }
        #pragma unroll
        for (int m2 = 0; m2 < 6; ++m2) yu[cq * 6 + m2] = pack2(yl[2 * m2], yl[2 * m2 + 1]);
    }
    ws_pre[gpix] = (am > 0.1f) ? (unsigned char)1 : (unsigned char)0;

    __syncthreads();  // weights staged; the only block barrier

    const unsigned short* wl = (const unsigned short*)wsm;  // frag f at wl + f*512
    unsigned short* yfw = yfs + wv * (2 * 528);

    // h-transpose shuffle geometry: dest lane (li,lq) pulls packed h-words of
    // pixel li from lanes srcA/srcB, register set chosen by lq>=2.
    const int srcA = li + (lq & 1) * 32;
    const int srcB = srcA + 16;
    const bool hiq = (lq >= 2);

    // wave-private dataflow: no block barriers inside this loop
    #pragma unroll
    for (int s = 0; s < 4; ++s) {
        const int t = wv * 4 + s;
        if ((ty & 3) == s) {
            #pragma unroll
            for (int q = 0; q < 4; ++q)
                *(uint4*)(yfw + (q * 16 + tx) * 8) = make_uint4(yu[q * 4], yu[q * 4 + 1], yu[q * 4 + 2], yu[q * 4 + 3]);
            *(uint4*)(yfw + 528 + (0 * 16 + tx) * 8) = make_uint4(yu[16], yu[17], yu[18], yu[19]);
            *(uint4*)(yfw + 528 + (1 * 16 + tx) * 8) = make_uint4(yu[20], yu[21], yu[22], yu[23]);
            *(uint4*)(yfw + 528 + (2 * 16 + tx) * 8) = make_uint4(0x3F80u, 0u, 0u, 0u);  // bias row k=48 -> 1.0
            *(uint4*)(yfw + 528 + (3 * 16 + tx) * 8) = make_uint4(0u, 0u, 0u, 0u);
        }
        const s8b ya0 = *(const s8b*)(yfw + lane * 8);
        const s8b ya1 = *(const s8b*)(yfw + 528 + lane * 8);

        f4 acc1[8];
        #pragma unroll
        for (int mt = 0; mt < 8; ++mt) { f4 z = {0.f, 0.f, 0.f, 0.f}; acc1[mt] = z; }
        #pragma unroll
        for (int mt = 0; mt < 8; ++mt) {
            const s8b wf = *(const s8b*)(wl + mt * 512 + lane * 8);
            acc1[mt] = __builtin_amdgcn_mfma_f32_16x16x32_bf16(wf, ya0, acc1[mt], 0, 0, 0);
        }
        #pragma unroll
        for (int mt = 0; mt < 8; ++mt) {
            const s8b wf = *(const s8b*)(wl + (8 + mt) * 512 + lane * 8);
            acc1[mt] = __builtin_amdgcn_mfma_f32_16x16x32_bf16(wf, ya1, acc1[mt], 0, 0, 0);
        }

        // ---- second GEMM: h B-frag built by cross-lane shuffle (no LDS) ----
        f4 acc2[2];
        { f4 z = {0.f, 0.f, 0.f, 0.f}; acc2[0] = z; acc2[1] = z; }
        #pragma unroll
        for (int k2 = 0; k2 < 4; ++k2) {
            const f4 aE = acc1[2 * k2], aO = acc1[2 * k2 + 1];
            const unsigned int e0 = pack2(fmaxf(aE[0], 0.f), fmaxf(aE[1], 0.f));
            const unsigned int e1 = pack2(fmaxf(aE[2], 0.f), fmaxf(aE[3], 0.f));
            const unsigned int o0 = pack2(fmaxf(aO[0], 0.f), fmaxf(aO[1], 0.f));
            const unsigned int o1 = pack2(fmaxf(aO[2], 0.f), fmaxf(aO[3], 0.f));
            const unsigned int vE0A = (unsigned int)__shfl((int)e0, srcA, 64);
            const unsigned int vE1A = (unsigned int)__shfl((int)e1, srcA, 64);
            const unsigned int vO0A = (unsigned int)__shfl((int)o0, srcA, 64);
            const unsigned int vO1A = (unsigned int)__shfl((int)o1, srcA, 64);
            const unsigned int vE0B = (unsigned int)__shfl((int)e0, srcB, 64);
            const unsigned int vE1B = (unsigned int)__shfl((int)e1, srcB, 64);
            const unsigned int vO0B = (unsigned int)__shfl((int)o0, srcB, 64);
            const unsigned int vO1B = (unsigned int)__shfl((int)o1, srcB, 64);
            union { uint4 u; s8b v; } hb;
            hb.u = make_uint4(hiq ? vO0A : vE0A, hiq ? vO1A : vE1A,
                              hiq ? vO0B : vE0B, hiq ? vO1B : vE1B);
            const s8b w2fr = *(const s8b*)(wl + 8192 + k2 * 512 + lane * 8);
            acc2[k2 >> 1] = __builtin_amdgcn_mfma_f32_16x16x32_bf16(w2fr, hb.v, acc2[k2 >> 1], 0, 0, 0);
        }

        const size_t gp = ((size_t)bb * 256 + h0 + t) * 256 + (w0 + li);
        const float um = (rand_u[gp] <= 0.5f) ? 1.f : 0.f;
        const f4 xc = *((const f4*)x + gp * 4 + lq);   // coalesced, L2/L3-hit
        f4 nx;
        nx[0] = fmaf(acc2[0][0] + acc2[1][0] + b2v[0], um, xc[0]);
        nx[1] = fmaf(acc2[0][1] + acc2[1][1] + b2v[1], um, xc[1]);
        nx[2] = fmaf(acc2[0][2] + acc2[1][2] + b2v[2], um, xc[2]);
        nx[3] = fmaf(acc2[0][3] + acc2[1][3] + b2v[3], um, xc[3]);
        __builtin_nontemporal_store(nx, (f4*)out + gp * 4 + lq);
        if (lq == 0) {
            ws_alpha[gp] = nx[3];
            // near-threshold updated pixels -> exact-recompute worklist
            if (um != 0.f && fabsf(nx[3] - 0.1f) <= MG) {
                unsigned int idx = atomicAdd(fix_cnt, 1u);
                if (idx < MAXFIX) fix_list[idx] = (unsigned int)gp;
            }
        }
    }
}

// ---------------- fixup: exact fp32 alpha for worklist pixels ----------------
__global__ __launch_bounds__(64) void ca_fix(
    const float* __restrict__ x, const float* __restrict__ W1,
    const float* __restrict__ b1, const float* __restrict__ W2,
    const float* __restrict__ b2,
    const unsigned int* __restrict__ fix_cnt, const unsigned int* __restrict__ fix_list,
    float* __restrict__ ws_alpha)
{
    __shared__ float ysh[48];
    const int lane = threadIdx.x;
    unsigned int n = *fix_cnt;
    if (n > MAXFIX) n = MAXFIX;
    for (unsigned int e = blockIdx.x; e < n; e += gridDim.x) {
        const unsigned int pix = fix_list[e];
        const int bb = pix >> 16, h = (pix >> 8) & 255, w = pix & 255;
        if (lane < 48) {
            const int c = lane / 3, j = lane - c * 3;
            float v = 0.f;
            #pragma unroll
            for (int dy = 0; dy < 3; ++dy) {
                #pragma unroll
                for (int dxx = 0; dxx < 3; ++dxx) {
                    const int hh = h + dy - 1, ww = w + dxx - 1;
                    if (hh < 0 || hh >= 256 || ww < 0 || ww >= 256) continue;
                    const float f = x[(((size_t)bb * 256 + hh) * 256 + ww) * 16 + c];
                    float wgt;
                    if (j == 0) wgt = (dy == 1 && dxx == 1) ? 1.f : 0.f;
                    else if (j == 1) wgt = ((dy == 1) ? 2.f : 1.f) * (float)(dxx - 1) * 0.125f;
                    else wgt = ((dxx == 1) ? 2.f : 1.f) * (float)(dy - 1) * 0.125f;
                    v = fmaf(f, wgt, v);
                }
            }
            ysh[lane] = v;
        }
        __syncthreads();
        float dot = 0.f;
        #pragma unroll
        for (int t = 0; t < 2; ++t) {
            const int d = t * 64 + lane;
            float a = b1[d];
            #pragma unroll
            for (int k = 0; k < 48; ++k)
                a = fmaf(ysh[k], W1[k * 128 + d], a);
            dot = fmaf(fmaxf(a, 0.f), W2[d * 16 + 3], dot);
        }
        #pragma unroll
        for (int off = 32; off > 0; off >>= 1)
            dot += __shfl_down(dot, off, 64);
        if (lane == 0)
            ws_alpha[pix] = x[(size_t)pix * 16 + 3] + dot + b2[3];
        __syncthreads();
    }
}

// ---------------- mask: 3x3 max, zero dead pixels only ----------------
__global__ __launch_bounds__(256) void ca_mask(
    const float* __restrict__ alpha, const unsigned char* __restrict__ pre,
    float* __restrict__ out)
{
    __shared__ float at[18 * 20];
    const int tid = threadIdx.x;
    const int w0 = blockIdx.x * 16, h0 = blockIdx.y * 16, bb = blockIdx.z;
    for (int i = tid; i < 324; i += 256) {
        const int ly = i / 18, lx = i - ly * 18;
        const int gh = h0 + ly - 1, gw = w0 + lx - 1;
        float v = 0.f;
        if (gh >= 0 && gh < 256 && gw >= 0 && gw < 256)
            v = alpha[((size_t)bb * 256 + gh) * 256 + gw];
        at[ly * 20 + lx] = v;
    }
    __syncthreads();
    const int txx = tid & 15, tyy = tid >> 4;
    float m = at[tyy * 20 + txx];
    m = fmaxf(m, at[tyy * 20 + txx + 1]); m = fmaxf(m, at[tyy * 20 + txx + 2]);
    m = fmaxf(m, at[(tyy + 1) * 20 + txx]); m = fmaxf(m, at[(tyy + 1) * 20 + txx + 1]); m = fmaxf(m, at[(tyy + 1) * 20 + txx + 2]);
    m = fmaxf(m, at[(tyy + 2) * 20 + txx]); m = fmaxf(m, at[(tyy + 2) * 20 + txx + 1]); m = fmaxf(m, at[(tyy + 2) * 20 + txx + 2]);
    const size_t gp = ((size_t)bb * 256 + h0 + tyy) * 256 + (w0 + txx);
    const bool alive = (m > 0.1f) && pre[gp];
    if (!alive) {
        float4* po = (float4*)(out + gp * 16);
        const float4 z = make_float4(0.f, 0.f, 0.f, 0.f);
        po[0] = z; po[1] = z; po[2] = z; po[3] = z;
    }
}

extern "C" void kernel_launch(void* const* d_in, const int* in_sizes, int n_in,
                              void* d_out, int out_size, void* d_ws, size_t ws_size,
                              hipStream_t stream) {
    (void)in_sizes; (void)n_in; (void)out_size; (void)ws_size;
    const float* x  = (const float*)d_in[0];
    const float* W1 = (const float*)d_in[1];
    const float* b1 = (const float*)d_in[2];
    const float* W2 = (const float*)d_in[3];
    const float* b2 = (const float*)d_in[4];
    const float* ru = (const float*)d_in[5];
    float* out = (float*)d_out;

    char* ws = (char*)d_ws;
    float* ws_alpha       = (float*)ws;                                // 4 MiB
    unsigned char* ws_pre = (unsigned char*)(ws + (size_t)NPIX * 4);   // 1 MiB
    uint4* w1p            = (uint4*)(ws + (size_t)NPIX * 5);           // 16 KiB
    uint4* w2p            = w1p + 1024;                                // 4 KiB (contiguous after w1p)
    unsigned int* fix_cnt = (unsigned int*)(ws + (size_t)NPIX * 5 + 20480);
    unsigned int* fix_list= fix_cnt + 4;                               // 256 KiB

    (void)hipMemsetAsync(fix_cnt, 0, sizeof(unsigned int), stream);
    ca_prep<<<2, 256, 0, stream>>>(W1, b1, W2, w1p, w2p);
    dim3 g(16, 16, 16);
    ca_update<<<g, 256, 0, stream>>>(x, b2, ru, w1p, w2p, out, ws_alpha, ws_pre, fix_cnt, fix_list);
    ca_fix<<<4096, 64, 0, stream>>>(x, W1, b1, W2, b2, fix_cnt, fix_list, ws_alpha);
    ca_mask<<<g, 256, 0, stream>>>(ws_alpha, ws_pre, out);
}

// Round 9
// 331.938 us; speedup vs baseline: 1.2455x; 1.2455x over previous
//
#include <hip/hip_runtime.h>

// Neural-CA update step, MI355X/gfx950.
// ca_prep: pack W1(+b1)/W2 into MFMA bf16 fragments in d_ws.
// ca_update: 16x16 tile, fp32 perceive -> bf16 MFMA MLP -> out, ws_alpha, ws_pre.
//   v9 = best-of-8-rounds synthesis:
//     * v1's coalesced xtile staging + LDS perceive (v8 proved global-perceive
//       costs ~90us of L2 latency)
//     * v8's spill-free register profile: weights in a SEPARATE LDS region
//       (no union, no xcr -- epilogue xc reads the still-live xtile), rand_u
//       read direct in epilogue (no lsr)
//     * shuffle h-transpose (no 17.4KB hbs, no per-s LDS round-trip)
//     * yfs shrunk 8448->6144B: ya1's bias/zero rows (lq>=2) are compile-time
//       constants, not stored -> LDS total 52,544B -> 3 blocks/CU
//     * ONE barrier in the whole kernel
// ca_fix: one wave per worklist entry recomputes exact fp32 alpha.
// ca_mask: branchless 3x3 max; only ZEROES dead pixels.

#define NC 16
#define NHID 128
#define NPIX (16 * 256 * 256)
#define MG 0.04f
#define MAXFIX 65536

typedef __attribute__((ext_vector_type(8))) short s8b;   // 8 x bf16 (4 VGPRs)
typedef __attribute__((ext_vector_type(4))) float f4;

__device__ __forceinline__ unsigned short f2bf(float f) {
    union { float f; unsigned int u; } v; v.f = f;
    unsigned int r = (v.u + 0x7FFFu + ((v.u >> 16) & 1u)) >> 16;  // RNE
    return (unsigned short)r;
}
__device__ __forceinline__ unsigned int pack2(float a, float b) {
    return (unsigned int)f2bf(a) | ((unsigned int)f2bf(b) << 16);
}

// ---------------- prep: pack weights into MFMA fragment order ----------------
__global__ __launch_bounds__(256) void ca_prep(
    const float* __restrict__ W1, const float* __restrict__ b1,
    const float* __restrict__ W2, uint4* __restrict__ w1p, uint4* __restrict__ w2p)
{
    const int tid = threadIdx.x;
    if (blockIdx.x == 0) {
        for (int idx = tid; idx < 1024; idx += 256) {
            const int fid = idx >> 6, lane = idx & 63;
            const int k0 = fid >> 3, mt = fid & 7;
            const int q = lane >> 4, i = lane & 15;
            unsigned int u[4];
            #pragma unroll
            for (int jp = 0; jp < 4; ++jp) {
                int k = k0 * 32 + q * 8 + jp * 2;
                float v0 = (k < 48) ? W1[k * 128 + mt * 16 + i] : ((k == 48) ? b1[mt * 16 + i] : 0.f);
                k++;
                float v1 = (k < 48) ? W1[k * 128 + mt * 16 + i] : ((k == 48) ? b1[mt * 16 + i] : 0.f);
                u[jp] = pack2(v0, v1);
            }
            w1p[idx] = make_uint4(u[0], u[1], u[2], u[3]);
        }
    } else {
        for (int idx = tid; idx < 256; idx += 256) {
            const int k2 = idx >> 6, lane = idx & 63;
            const int q = lane >> 4, i = lane & 15;
            unsigned int u[4];
            #pragma unroll
            for (int jp = 0; jp < 4; ++jp) {
                const int k = k2 * 32 + q * 8 + jp * 2;
                u[jp] = pack2(W2[k * 16 + i], W2[(k + 1) * 16 + i]);
            }
            w2p[idx] = make_uint4(u[0], u[1], u[2], u[3]);
        }
    }
}

// ---------------- main update kernel ----------------
__global__ __launch_bounds__(256, 3) void ca_update(
    const float* __restrict__ x, const float* __restrict__ b2,
    const float* __restrict__ rand_u, const uint4* __restrict__ w1p,
    const uint4* __restrict__ w2p, float* __restrict__ out,
    float* __restrict__ ws_alpha, unsigned char* __restrict__ ws_pre,
    unsigned int* __restrict__ fix_cnt, unsigned int* __restrict__ fix_list)
{
    __shared__ __align__(16) float xt[18 * 18 * 20];           // 25,920 B halo tile
    __shared__ __align__(16) uint4 wsm[1280];                  // 20,480 B weights
    __shared__ __align__(16) unsigned short yfs[4 * 768];      //  6,144 B y B-frags

    const int tid  = threadIdx.x;
    const int lane = tid & 63;
    const int li   = lane & 15;
    const int lq   = lane >> 4;
    const int wv   = tid >> 6;
    const int tx   = tid & 15, ty = tid >> 4;
    const int w0 = blockIdx.x * 16, h0 = blockIdx.y * 16, bb = blockIdx.z;

    // ---- stage weight fragments into LDS (w2p contiguous after w1p) ----
    for (int i = tid; i < 1280; i += 256)
        wsm[i] = w1p[i];

    // ---- stage x halo tile (coalesced float4 x4) ----
    for (int i = tid; i < 324; i += 256) {
        const int ly = i / 18, lx = i - ly * 18;
        const int gh = h0 + ly - 1, gw = w0 + lx - 1;
        float4 v0, v1, v2, v3;
        if (gh >= 0 && gh < 256 && gw >= 0 && gw < 256) {
            const float4* p = (const float4*)(x + (((size_t)bb * 256 + gh) * 256 + gw) * NC);
            v0 = p[0]; v1 = p[1]; v2 = p[2]; v3 = p[3];
        } else {
            v0 = v1 = v2 = v3 = make_float4(0.f, 0.f, 0.f, 0.f);
        }
        float4* t = (float4*)(xt + i * 20);
        t[0] = v0; t[1] = v1; t[2] = v2; t[3] = v3;
    }

    float b2v[4];
    #pragma unroll
    for (int r = 0; r < 4; ++r) b2v[r] = b2[lq * 4 + r];

    __syncthreads();  // the only block barrier

    // ---- pre-mask (exact fp32) ----
    const int o_mm = ((ty + 0) * 18 + tx + 0) * 20, o_m0 = ((ty + 0) * 18 + tx + 1) * 20, o_mp = ((ty + 0) * 18 + tx + 2) * 20;
    const int o_0m = ((ty + 1) * 18 + tx + 0) * 20, o_cc = ((ty + 1) * 18 + tx + 1) * 20, o_0p = ((ty + 1) * 18 + tx + 2) * 20;
    const int o_pm = ((ty + 2) * 18 + tx + 0) * 20, o_p0 = ((ty + 2) * 18 + tx + 1) * 20, o_pp = ((ty + 2) * 18 + tx + 2) * 20;

    const size_t gpix = ((size_t)bb * 256 + h0 + ty) * 256 + (w0 + tx);
    float am = xt[o_mm + 3];
    am = fmaxf(am, xt[o_m0 + 3]); am = fmaxf(am, xt[o_mp + 3]);
    am = fmaxf(am, xt[o_0m + 3]); am = fmaxf(am, xt[o_cc + 3]); am = fmaxf(am, xt[o_0p + 3]);
    am = fmaxf(am, xt[o_pm + 3]); am = fmaxf(am, xt[o_p0 + 3]); am = fmaxf(am, xt[o_pp + 3]);
    ws_pre[gpix] = (am > 0.1f) ? (unsigned char)1 : (unsigned char)0;

    // ---- perceive (fp32, from LDS) -> packed bf16 y-words ----
    unsigned int yu[24];
    #pragma unroll
    for (int cq = 0; cq < 4; ++cq) {
        const int co = cq * 4;
        float4 vmm = *(const float4*)(xt + o_mm + co); const float* pmm = (const float*)&vmm;
        float4 vm0 = *(const float4*)(xt + o_m0 + co); const float* pm0 = (const float*)&vm0;
        float4 vmp = *(const float4*)(xt + o_mp + co); const float* pmp = (const float*)&vmp;
        float4 v0m = *(const float4*)(xt + o_0m + co); const float* p0m = (const float*)&v0m;
        float4 vcc = *(const float4*)(xt + o_cc + co); const float* pcc = (const float*)&vcc;
        float4 v0p = *(const float4*)(xt + o_0p + co); const float* p0p = (const float*)&v0p;
        float4 vpm = *(const float4*)(xt + o_pm + co); const float* ppm = (const float*)&vpm;
        float4 vp0 = *(const float4*)(xt + o_p0 + co); const float* pp0 = (const float*)&vp0;
        float4 vpp = *(const float4*)(xt + o_pp + co); const float* ppp = (const float*)&vpp;
        float yl[12];
        #pragma unroll
        for (int cc = 0; cc < 4; ++cc) {
            const float xmm = pmm[cc], xm0 = pm0[cc], xmp = pmp[cc];
            const float x0m = p0m[cc], xcc = pcc[cc], x0p = p0p[cc];
            const float xpm = ppm[cc], xp0 = pp0[cc], xpp = ppp[cc];
            yl[cc * 3 + 0] = xcc;
            yl[cc * 3 + 1] = ((xmp - xmm) + 2.f * (x0p - x0m) + (xpp - xpm)) * 0.125f;
            yl[cc * 3 + 2] = ((xpm - xmm) + 2.f * (xp0 - xm0) + (xpp - xmp)) * 0.125f;
        }
        #pragma unroll
        for (int m2 = 0; m2 < 6; ++m2) yu[cq * 6 + m2] = pack2(yl[2 * m2], yl[2 * m2 + 1]);
    }

    const unsigned short* wl = (const unsigned short*)wsm;  // frag f at wl + f*512
    unsigned short* yfw = yfs + wv * 768;

    // h-transpose shuffle geometry: dest lane (li,lq) pulls packed h-words of
    // pixel li from lanes srcA/srcB, register set chosen by lq>=2.
    const int srcA = li + (lq & 1) * 32;
    const int srcB = srcA + 16;
    const bool hiq = (lq >= 2);

    // wave-private dataflow: no block barriers inside this loop
    #pragma unroll
    for (int s = 0; s < 4; ++s) {
        const int t = wv * 4 + s;
        if ((ty & 3) == s) {
            #pragma unroll
            for (int q = 0; q < 4; ++q)
                *(uint4*)(yfw + (q * 16 + tx) * 8) = make_uint4(yu[q * 4], yu[q * 4 + 1], yu[q * 4 + 2], yu[q * 4 + 3]);
            *(uint4*)(yfw + 512 + (0 * 16 + tx) * 8) = make_uint4(yu[16], yu[17], yu[18], yu[19]);
            *(uint4*)(yfw + 512 + (1 * 16 + tx) * 8) = make_uint4(yu[20], yu[21], yu[22], yu[23]);
            // ya1 rows for lq>=2 (bias k=48 -> 1.0, and zeros) are NOT stored:
            // they are compile-time constants materialized at the read.
        }
        const s8b ya0 = *(const s8b*)(yfw + lane * 8);
        s8b ya1;
        if (lq < 2) {
            ya1 = *(const s8b*)(yfw + 512 + (lq * 16 + li) * 8);
        } else if (lq == 2) {
            const s8b c = {(short)0x3F80, 0, 0, 0, 0, 0, 0, 0};  // bias row k=48 -> 1.0
            ya1 = c;
        } else {
            const s8b c = {0, 0, 0, 0, 0, 0, 0, 0};
            ya1 = c;
        }

        f4 acc1[8];
        #pragma unroll
        for (int mt = 0; mt < 8; ++mt) { f4 z = {0.f, 0.f, 0.f, 0.f}; acc1[mt] = z; }
        #pragma unroll
        for (int mt = 0; mt < 8; ++mt) {
            const s8b wf = *(const s8b*)(wl + mt * 512 + lane * 8);
            acc1[mt] = __builtin_amdgcn_mfma_f32_16x16x32_bf16(wf, ya0, acc1[mt], 0, 0, 0);
        }
        #pragma unroll
        for (int mt = 0; mt < 8; ++mt) {
            const s8b wf = *(const s8b*)(wl + (8 + mt) * 512 + lane * 8);
            acc1[mt] = __builtin_amdgcn_mfma_f32_16x16x32_bf16(wf, ya1, acc1[mt], 0, 0, 0);
        }

        // ---- second GEMM: h B-frag built by cross-lane shuffle (no LDS) ----
        f4 acc2[2];
        { f4 z = {0.f, 0.f, 0.f, 0.f}; acc2[0] = z; acc2[1] = z; }
        #pragma unroll
        for (int k2 = 0; k2 < 4; ++k2) {
            const f4 aE = acc1[2 * k2], aO = acc1[2 * k2 + 1];
            const unsigned int e0 = pack2(fmaxf(aE[0], 0.f), fmaxf(aE[1], 0.f));
            const unsigned int e1 = pack2(fmaxf(aE[2], 0.f), fmaxf(aE[3], 0.f));
            const unsigned int o0 = pack2(fmaxf(aO[0], 0.f), fmaxf(aO[1], 0.f));
            const unsigned int o1 = pack2(fmaxf(aO[2], 0.f), fmaxf(aO[3], 0.f));
            const unsigned int vE0A = (unsigned int)__shfl((int)e0, srcA, 64);
            const unsigned int vE1A = (unsigned int)__shfl((int)e1, srcA, 64);
            const unsigned int vO0A = (unsigned int)__shfl((int)o0, srcA, 64);
            const unsigned int vO1A = (unsigned int)__shfl((int)o1, srcA, 64);
            const unsigned int vE0B = (unsigned int)__shfl((int)e0, srcB, 64);
            const unsigned int vE1B = (unsigned int)__shfl((int)e1, srcB, 64);
            const unsigned int vO0B = (unsigned int)__shfl((int)o0, srcB, 64);
            const unsigned int vO1B = (unsigned int)__shfl((int)o1, srcB, 64);
            union { uint4 u; s8b v; } hb;
            hb.u = make_uint4(hiq ? vO0A : vE0A, hiq ? vO1A : vE1A,
                              hiq ? vO0B : vE0B, hiq ? vO1B : vE1B);
            const s8b w2fr = *(const s8b*)(wl + 8192 + k2 * 512 + lane * 8);
            acc2[k2 >> 1] = __builtin_amdgcn_mfma_f32_16x16x32_bf16(w2fr, hb.v, acc2[k2 >> 1], 0, 0, 0);
        }

        const size_t gp = ((size_t)bb * 256 + h0 + t) * 256 + (w0 + li);
        const float um = (rand_u[gp] <= 0.5f) ? 1.f : 0.f;
        const f4 xc = *(const f4*)(xt + ((t + 1) * 18 + li + 1) * 20 + lq * 4);  // tile still live
        f4 nx;
        nx[0] = fmaf(acc2[0][0] + acc2[1][0] + b2v[0], um, xc[0]);
        nx[1] = fmaf(acc2[0][1] + acc2[1][1] + b2v[1], um, xc[1]);
        nx[2] = fmaf(acc2[0][2] + acc2[1][2] + b2v[2], um, xc[2]);
        nx[3] = fmaf(acc2[0][3] + acc2[1][3] + b2v[3], um, xc[3]);
        __builtin_nontemporal_store(nx, (f4*)out + gp * 4 + lq);
        if (lq == 0) {
            ws_alpha[gp] = nx[3];
            // near-threshold updated pixels -> exact-recompute worklist
            if (um != 0.f && fabsf(nx[3] - 0.1f) <= MG) {
                unsigned int idx = atomicAdd(fix_cnt, 1u);
                if (idx < MAXFIX) fix_list[idx] = (unsigned int)gp;
            }
        }
    }
}

// ---------------- fixup: exact fp32 alpha for worklist pixels ----------------
__global__ __launch_bounds__(64) void ca_fix(
    const float* __restrict__ x, const float* __restrict__ W1,
    const float* __restrict__ b1, const float* __restrict__ W2,
    const float* __restrict__ b2,
    const unsigned int* __restrict__ fix_cnt, const unsigned int* __restrict__ fix_list,
    float* __restrict__ ws_alpha)
{
    __shared__ float ysh[48];
    const int lane = threadIdx.x;
    unsigned int n = *fix_cnt;
    if (n > MAXFIX) n = MAXFIX;
    for (unsigned int e = blockIdx.x; e < n; e += gridDim.x) {
        const unsigned int pix = fix_list[e];
        const int bb = pix >> 16, h = (pix >> 8) & 255, w = pix & 255;
        if (lane < 48) {
            const int c = lane / 3, j = lane - c * 3;
            float v = 0.f;
            #pragma unroll
            for (int dy = 0; dy < 3; ++dy) {
                #pragma unroll
                for (int dxx = 0; dxx < 3; ++dxx) {
                    const int hh = h + dy - 1, ww = w + dxx - 1;
                    if (hh < 0 || hh >= 256 || ww < 0 || ww >= 256) continue;
                    const float f = x[(((size_t)bb * 256 + hh) * 256 + ww) * 16 + c];
                    float wgt;
                    if (j == 0) wgt = (dy == 1 && dxx == 1) ? 1.f : 0.f;
                    else if (j == 1) wgt = ((dy == 1) ? 2.f : 1.f) * (float)(dxx - 1) * 0.125f;
                    else wgt = ((dxx == 1) ? 2.f : 1.f) * (float)(dy - 1) * 0.125f;
                    v = fmaf(f, wgt, v);
                }
            }
            ysh[lane] = v;
        }
        __syncthreads();
        float dot = 0.f;
        #pragma unroll
        for (int t = 0; t < 2; ++t) {
            const int d = t * 64 + lane;
            float a = b1[d];
            #pragma unroll
            for (int k = 0; k < 48; ++k)
                a = fmaf(ysh[k], W1[k * 128 + d], a);
            dot = fmaf(fmaxf(a, 0.f), W2[d * 16 + 3], dot);
        }
        #pragma unroll
        for (int off = 32; off > 0; off >>= 1)
            dot += __shfl_down(dot, off, 64);
        if (lane == 0)
            ws_alpha[pix] = x[(size_t)pix * 16 + 3] + dot + b2[3];
        __syncthreads();
    }
}

// ---------------- mask: 3x3 max, zero dead pixels only ----------------
__global__ __launch_bounds__(256) void ca_mask(
    const float* __restrict__ alpha, const unsigned char* __restrict__ pre,
    float* __restrict__ out)
{
    __shared__ float at[18 * 20];
    const int tid = threadIdx.x;
    const int w0 = blockIdx.x * 16, h0 = blockIdx.y * 16, bb = blockIdx.z;
    for (int i = tid; i < 324; i += 256) {
        const int ly = i / 18, lx = i - ly * 18;
        const int gh = h0 + ly - 1, gw = w0 + lx - 1;
        float v = 0.f;
        if (gh >= 0 && gh < 256 && gw >= 0 && gw < 256)
            v = alpha[((size_t)bb * 256 + gh) * 256 + gw];
        at[ly * 20 + lx] = v;
    }
    __syncthreads();
    const int txx = tid & 15, tyy = tid >> 4;
    float m = at[tyy * 20 + txx];
    m = fmaxf(m, at[tyy * 20 + txx + 1]); m = fmaxf(m, at[tyy * 20 + txx + 2]);
    m = fmaxf(m, at[(tyy + 1) * 20 + txx]); m = fmaxf(m, at[(tyy + 1) * 20 + txx + 1]); m = fmaxf(m, at[(tyy + 1) * 20 + txx + 2]);
    m = fmaxf(m, at[(tyy + 2) * 20 + txx]); m = fmaxf(m, at[(tyy + 2) * 20 + txx + 1]); m = fmaxf(m, at[(tyy + 2) * 20 + txx + 2]);
    const size_t gp = ((size_t)bb * 256 + h0 + tyy) * 256 + (w0 + txx);
    const bool alive = (m > 0.1f) && pre[gp];
    if (!alive) {
        float4* po = (float4*)(out + gp * 16);
        const float4 z = make_float4(0.f, 0.f, 0.f, 0.f);
        po[0] = z; po[1] = z; po[2] = z; po[3] = z;
    }
}

extern "C" void kernel_launch(void* const* d_in, const int* in_sizes, int n_in,
                              void* d_out, int out_size, void* d_ws, size_t ws_size,
                              hipStream_t stream) {
    (void)in_sizes; (void)n_in; (void)out_size; (void)ws_size;
    const float* x  = (const float*)d_in[0];
    const float* W1 = (const float*)d_in[1];
    const float* b1 = (const float*)d_in[2];
    const float* W2 = (const float*)d_in[3];
    const float* b2 = (const float*)d_in[4];
    const float* ru = (const float*)d_in[5];
    float* out = (float*)d_out;

    char* ws = (char*)d_ws;
    float* ws_alpha       = (float*)ws;                                // 4 MiB
    unsigned char* ws_pre = (unsigned char*)(ws + (size_t)NPIX * 4);   // 1 MiB
    uint4* w1p            = (uint4*)(ws + (size_t)NPIX * 5);           // 16 KiB
    uint4* w2p            = w1p + 1024;                                // 4 KiB (contiguous after w1p)
    unsigned int* fix_cnt = (unsigned int*)(ws + (size_t)NPIX * 5 + 20480);
    unsigned int* fix_list= fix_cnt + 4;                               // 256 KiB

    (void)hipMemsetAsync(fix_cnt, 0, sizeof(unsigned int), stream);
    ca_prep<<<2, 256, 0, stream>>>(W1, b1, W2, w1p, w2p);
    dim3 g(16, 16, 16);
    ca_update<<<g, 256, 0, stream>>>(x, b2, ru, w1p, w2p, out, ws_alpha, ws_pre, fix_cnt, fix_list);
    ca_fix<<<4096, 64, 0, stream>>>(x, W1, b1, W2, b2, fix_cnt, fix_list, ws_alpha);
    ca_mask<<<g, 256, 0, stream>>>(ws_alpha, ws_pre, out);
}